// Round 1
// baseline (1027.263 us; speedup 1.0000x reference)
//
#include <hip/hip_runtime.h>

#define CB 64
#define CN 4096
#define CD 256
#define CS 8
#define CH 512

typedef __bf16 bf16_t;
typedef bf16_t bf16x8 __attribute__((ext_vector_type(8)));
typedef float f32x4 __attribute__((ext_vector_type(4)));

__device__ __forceinline__ unsigned short f2bf(float f){
  unsigned int u = __builtin_bit_cast(unsigned int, f);
  u += 0x7FFFu + ((u >> 16) & 1u);
  return (unsigned short)(u >> 16);
}

__device__ __forceinline__ f32x4 mfma16(bf16x8 a, bf16x8 b, f32x4 c){
  return __builtin_amdgcn_mfma_f32_16x16x32_bf16(a, b, c, 0, 0, 0);
}

__device__ __forceinline__ void gl_lds16(const void* g, void* l){
  __builtin_amdgcn_global_load_lds(
      (const __attribute__((address_space(1))) unsigned int*)g,
      (__attribute__((address_space(3))) unsigned int*)l, 16, 0, 0);
}

// ---------------- LN over inputs -> x (bf16, row-major) ----------------
__global__ __launch_bounds__(256) void k_ln(const float* __restrict__ in,
    const float* __restrict__ gw, const float* __restrict__ gb,
    unsigned short* __restrict__ x){
  int blk = blockIdx.x;            // 4096 = 64 b * 64 ntiles
  int b = blk >> 6, nt = blk & 63;
  int wv = threadIdx.x >> 6, l = threadIdx.x & 63;
  const float* base = in + ((size_t)b*CN + (size_t)nt*64) * CD;
  unsigned short* xb = x + ((size_t)b*CN + (size_t)nt*64) * CD;
  float4 w4 = *(const float4*)(gw + 4*l);
  float4 b4 = *(const float4*)(gb + 4*l);
  for(int i = 0; i < 16; i++){
    int r = wv*16 + i;
    float4 v = *(const float4*)(base + (size_t)r*CD + 4*l);
    float s1 = v.x + v.y + v.z + v.w;
    float s2 = v.x*v.x + v.y*v.y + v.z*v.z + v.w*v.w;
    #pragma unroll
    for(int m = 1; m < 64; m <<= 1){ s1 += __shfl_xor(s1, m); s2 += __shfl_xor(s2, m); }
    float mean = s1 * (1.0f/CD);
    float var  = fmaxf(s2 * (1.0f/CD) - mean*mean, 0.0f);
    float rstd = rsqrtf(var + 1e-5f);
    float y0 = (v.x - mean)*rstd*w4.x + b4.x;
    float y1 = (v.y - mean)*rstd*w4.y + b4.y;
    float y2 = (v.z - mean)*rstd*w4.z + b4.z;
    float y3 = (v.w - mean)*rstd*w4.w + b4.w;
    uint2 p;
    p.x = (unsigned)f2bf(y0) | ((unsigned)f2bf(y1) << 16);
    p.y = (unsigned)f2bf(y2) | ((unsigned)f2bf(y3) << 16);
    *(uint2*)(xb + (size_t)r*CD + 4*l) = p;
  }
}

// ---------------- slots init ----------------
__global__ __launch_bounds__(256) void k_slots0(const float* __restrict__ noise,
    const float* __restrict__ mu, const float* __restrict__ lsig, float* __restrict__ slots){
  int i = blockIdx.x*256 + threadIdx.x;   // 131072
  int d = i & 255;
  slots[i] = mu[d] + __expf(lsig[d]) * noise[i];
}

// ---------------- M1T[ep][e] = scale * sum_d Wq[d][e]*Wk[d][ep]  (bf16) ----------------
__global__ __launch_bounds__(256) void k_m1t(const float* __restrict__ Wq,
    const float* __restrict__ Wk, unsigned short* __restrict__ M1T){
  int ep = blockIdx.x, e = threadIdx.x;
  float acc = 0.0f;
  for(int d = 0; d < 256; d++) acc = fmaf(Wq[(size_t)d*256 + e], Wk[(size_t)d*256 + ep], acc);
  M1T[(size_t)ep*256 + e] = f2bf(acc * 0.0625f);
}

// ---------------- MihT[e][j] = sum_d wih[j][d]*Wv[d][e]  (fp32) ----------------
__global__ __launch_bounds__(256) void k_miht(const float* __restrict__ wih,
    const float* __restrict__ Wv, float* __restrict__ MihT){
  int j = blockIdx.x, e = threadIdx.x;
  float acc = 0.0f;
  for(int d = 0; d < 256; d++) acc = fmaf(wih[(size_t)j*256 + d], Wv[(size_t)d*256 + e], acc);
  MihT[(size_t)e*768 + j] = acc;
}

// ---------------- generic transpose: dst[c][r] = src[r][c] ----------------
__global__ void k_tr(const float* __restrict__ src, float* __restrict__ dst){
  int r = blockIdx.x, c = threadIdx.x;
  int R = gridDim.x, C = blockDim.x;
  dst[(size_t)c*R + r] = src[(size_t)r*C + c];
}

// ---------------- qt[b][s][ep] = scale * LN(slots) @ M1   (bf16, rows 8..15 zero) ----------------
__global__ __launch_bounds__(256) void k_qt(const float* __restrict__ slots,
    const float* __restrict__ lw, const float* __restrict__ lb,
    const unsigned short* __restrict__ M1T, unsigned short* __restrict__ qt){
  __shared__ unsigned short sn[16*264];
  int b = blockIdx.x;
  int wv = threadIdx.x >> 6, l = threadIdx.x & 63;
  int lm = l & 15, lg = l >> 4;
  float4 w4 = *(const float4*)(lw + 4*l);
  float4 b4 = *(const float4*)(lb + 4*l);
  for(int i = 0; i < 2; i++){
    int r = wv*2 + i;
    float4 v = *(const float4*)(slots + ((size_t)b*CS + r)*CD + 4*l);
    float s1 = v.x + v.y + v.z + v.w;
    float s2 = v.x*v.x + v.y*v.y + v.z*v.z + v.w*v.w;
    #pragma unroll
    for(int m = 1; m < 64; m <<= 1){ s1 += __shfl_xor(s1, m); s2 += __shfl_xor(s2, m); }
    float mean = s1 * (1.0f/CD);
    float var  = fmaxf(s2 * (1.0f/CD) - mean*mean, 0.0f);
    float rstd = rsqrtf(var + 1e-5f);
    float y0 = (v.x - mean)*rstd*w4.x + b4.x;
    float y1 = (v.y - mean)*rstd*w4.y + b4.y;
    float y2 = (v.z - mean)*rstd*w4.z + b4.z;
    float y3 = (v.w - mean)*rstd*w4.w + b4.w;
    uint2 p;
    p.x = (unsigned)f2bf(y0) | ((unsigned)f2bf(y1) << 16);
    p.y = (unsigned)f2bf(y2) | ((unsigned)f2bf(y3) << 16);
    *(uint2*)(&sn[r*264 + 4*l]) = p;
    uint2 z; z.x = 0u; z.y = 0u;
    *(uint2*)(&sn[(r+8)*264 + 4*l]) = z;
  }
  __syncthreads();
  bf16x8 af[8];
  #pragma unroll
  for(int k = 0; k < 8; k++) af[k] = *(const bf16x8*)(&sn[lm*264 + k*32 + lg*8]);
  #pragma unroll
  for(int ntile = 0; ntile < 4; ntile++){
    int ep = wv*64 + ntile*16 + lm;
    f32x4 acc = {0.f, 0.f, 0.f, 0.f};
    const unsigned short* mrow = M1T + (size_t)ep*CD;
    #pragma unroll
    for(int k = 0; k < 8; k++){
      bf16x8 bf = *(const bf16x8*)(mrow + k*32 + lg*8);
      acc = mfma16(af[k], bf, acc);
    }
    #pragma unroll
    for(int reg = 0; reg < 4; reg++){
      int s = lg*4 + reg;
      qt[((size_t)b*16 + s)*CD + ep] = f2bf(acc[reg]);
    }
  }
}

// ---------------- fused attention pass: logits -> softmax+eps -> U,den ----------------
__global__ __launch_bounds__(256) void k_attn(const unsigned short* __restrict__ x,
    const unsigned short* __restrict__ qt, float* __restrict__ U, float* __restrict__ den){
  __shared__ unsigned short xt[64*256];   // XOR-swizzled 16B chunks
  __shared__ unsigned short pt[16*72];    // P^T (slot-major), padded stride
  int b = blockIdx.x >> 3, chunk = blockIdx.x & 7;
  int wv = threadIdx.x >> 6, l = threadIdx.x & 63;
  int lm = l & 15, lg = l >> 4;

  // persistent qt B-fragments
  bf16x8 qb[8];
  const unsigned short* qrow = qt + ((size_t)b*16 + lm)*CD;
  #pragma unroll
  for(int k = 0; k < 8; k++) qb[k] = *(const bf16x8*)(qrow + k*32 + lg*8);

  f32x4 uacc[4];
  #pragma unroll
  for(int nt = 0; nt < 4; nt++){ f32x4 z = {0.f,0.f,0.f,0.f}; uacc[nt] = z; }
  float dacc = 0.0f;

  const unsigned short* xbatch = x + (size_t)b*CN*CD + (size_t)chunk*512*CD;

  for(int t = 0; t < 8; t++){
    const unsigned short* xtile = xbatch + (size_t)t*64*CD;
    __syncthreads();   // previous phase2 done before restaging
    // stage 16 rows per wave, 2 rows per call, swizzled on global side
    #pragma unroll
    for(int k2 = 0; k2 < 8; k2++){
      int r0 = wv*16 + k2*2;
      int row = r0 + (l >> 5);
      int c = l & 31;
      int f = (row >> 3) & 3;
      const unsigned short* g = xtile + (size_t)row*CD + (size_t)(c ^ f)*8;
      gl_lds16(g, &xt[r0*CD]);
    }
    __syncthreads();   // staging complete

    // phase 1: logits for this wave's 16 rows
    f32x4 c4 = {0.f, 0.f, 0.f, 0.f};
    int rowl = wv*16 + lm;
    int f1 = (rowl >> 3) & 3;
    #pragma unroll
    for(int k = 0; k < 8; k++){
      int cc = (k*4 + lg) ^ f1;
      bf16x8 a = *(const bf16x8*)(&xt[rowl*256 + cc*8]);
      c4 = mfma16(a, qb[k], c4);
    }
    // softmax over slots (lane's slot = lm, 4 rows in regs)
    float pv[4];
    #pragma unroll
    for(int reg = 0; reg < 4; reg++){
      float v = (lm < 8) ? c4[reg] : -1e30f;
      float mx = v;
      #pragma unroll
      for(int m = 1; m < 16; m <<= 1) mx = fmaxf(mx, __shfl_xor(mx, m));
      float e = __expf(v - mx);
      float s = e;
      #pragma unroll
      for(int m = 1; m < 16; m <<= 1) s += __shfl_xor(s, m);
      float p = (lm < 8) ? (e/s + 1e-8f) : 0.0f;
      dacc += p;
      pv[reg] = p;
    }
    int rbase = wv*16 + lg*4;
    unsigned int p01 = (unsigned)f2bf(pv[0]) | ((unsigned)f2bf(pv[1]) << 16);
    unsigned int p23 = (unsigned)f2bf(pv[2]) | ((unsigned)f2bf(pv[3]) << 16);
    *(unsigned int*)(&pt[lm*72 + rbase])     = p01;
    *(unsigned int*)(&pt[lm*72 + rbase + 2]) = p23;
    __syncthreads();   // PT ready

    // phase 2: U[s, e-slice] += P^T @ X  (wave covers 64 dims)
    #pragma unroll
    for(int ks = 0; ks < 2; ks++){
      bf16x8 a = *(const bf16x8*)(&pt[lm*72 + ks*32 + lg*8]);
      int rb = ks*32 + lg*8;
      int f2 = (rb >> 3) & 3;
      #pragma unroll
      for(int nt = 0; nt < 4; nt++){
        int e = wv*64 + nt*16 + lm;
        int cidx = ((e >> 3) ^ f2);
        bf16x8 bfr;
        #pragma unroll
        for(int j = 0; j < 8; j++){
          unsigned short tv = xt[(rb + j)*256 + cidx*8 + (e & 7)];
          bfr[j] = __builtin_bit_cast(bf16_t, tv);
        }
        uacc[nt] = mfma16(a, bfr, uacc[nt]);
      }
    }
  }

  // epilogue
  dacc += __shfl_xor(dacc, 16);
  dacc += __shfl_xor(dacc, 32);
  if(l < 8) atomicAdd(&den[b*CS + l], dacc);
  if(lg < 2){
    #pragma unroll
    for(int nt = 0; nt < 4; nt++){
      #pragma unroll
      for(int reg = 0; reg < 4; reg++){
        int s = lg*4 + reg;
        atomicAdd(&U[((size_t)b*CS + s)*CD + wv*64 + nt*16 + lm], uacc[nt][reg]);
      }
    }
  }
}

// ---------------- GRU cell (wave per row, Wv folded into MihT) ----------------
__global__ __launch_bounds__(256) void k_gru(const float* __restrict__ U,
    const float* __restrict__ den, const float* __restrict__ slots,
    const float* __restrict__ MihT, const float* __restrict__ WhhT,
    const float* __restrict__ bih, const float* __restrict__ bhh, float* __restrict__ hp){
  int wv = threadIdx.x >> 6, l = threadIdx.x & 63;
  int row = __builtin_amdgcn_readfirstlane(blockIdx.x*4 + wv);
  const float* Ur = U + (size_t)row*256;
  const float* Hr = slots + (size_t)row*256;
  float ai[3][4] = {{0}}; float ah[3][4] = {{0}};
  for(int e4 = 0; e4 < 256; e4 += 4){
    float4 u4 = *(const float4*)(Ur + e4);
    float4 h4 = *(const float4*)(Hr + e4);
    #pragma unroll
    for(int k = 0; k < 4; k++){
      float ue = (&u4.x)[k], he = (&h4.x)[k];
      const float* wi = MihT + (size_t)(e4 + k)*768 + 4*l;
      const float* wh = WhhT + (size_t)(e4 + k)*768 + 4*l;
      #pragma unroll
      for(int g = 0; g < 3; g++){
        float4 wg = *(const float4*)(wi + g*256);
        float4 vg = *(const float4*)(wh + g*256);
        #pragma unroll
        for(int i = 0; i < 4; i++){
          ai[g][i] = fmaf((&wg.x)[i], ue, ai[g][i]);
          ah[g][i] = fmaf((&vg.x)[i], he, ah[g][i]);
        }
      }
    }
  }
  float invd = 1.0f / den[row];
  float4 br = *(const float4*)(bih + 4*l);
  float4 bz = *(const float4*)(bih + 256 + 4*l);
  float4 bn = *(const float4*)(bih + 512 + 4*l);
  float4 cr = *(const float4*)(bhh + 4*l);
  float4 cz = *(const float4*)(bhh + 256 + 4*l);
  float4 cn = *(const float4*)(bhh + 512 + 4*l);
  float4 hc = *(const float4*)(Hr + 4*l);
  float4 o;
  #pragma unroll
  for(int i = 0; i < 4; i++){
    float gr = ai[0][i]*invd + (&br.x)[i] + ah[0][i] + (&cr.x)[i];
    float gz = ai[1][i]*invd + (&bz.x)[i] + ah[1][i] + (&cz.x)[i];
    float gn = ai[2][i]*invd + (&bn.x)[i];
    float hn = ah[2][i] + (&cn.x)[i];
    float r = 1.0f/(1.0f + __expf(-gr));
    float z = 1.0f/(1.0f + __expf(-gz));
    float n = tanhf(gn + r*hn);
    (&o.x)[i] = (1.0f - z)*n + z*(&hc.x)[i];
  }
  *(float4*)(hp + (size_t)row*256 + 4*l) = o;
}

// ---------------- LN + MLP + residual (wave per row) ----------------
__global__ __launch_bounds__(256) void k_mlp(const float* __restrict__ hp,
    const float* __restrict__ lw, const float* __restrict__ lb,
    const float* __restrict__ w1T, const float* __restrict__ b1,
    const float* __restrict__ w2T, const float* __restrict__ b2, float* __restrict__ slots){
  __shared__ float h1s[4*512];
  int wv = threadIdx.x >> 6, l = threadIdx.x & 63;
  int row = __builtin_amdgcn_readfirstlane(blockIdx.x*4 + wv);
  const float* Hr = hp + (size_t)row*256;
  float4 hv = *(const float4*)(Hr + 4*l);
  float s1 = hv.x + hv.y + hv.z + hv.w;
  float s2 = hv.x*hv.x + hv.y*hv.y + hv.z*hv.z + hv.w*hv.w;
  #pragma unroll
  for(int m = 1; m < 64; m <<= 1){ s1 += __shfl_xor(s1, m); s2 += __shfl_xor(s2, m); }
  float mean = s1 * (1.0f/CD);
  float var  = fmaxf(s2 * (1.0f/CD) - mean*mean, 0.0f);
  float rstd = rsqrtf(var + 1e-5f);

  float acc[8] = {0};
  for(int e4 = 0; e4 < 256; e4 += 4){
    float4 h4  = *(const float4*)(Hr + e4);
    float4 w4  = *(const float4*)(lw + e4);
    float4 b4  = *(const float4*)(lb + e4);
    #pragma unroll
    for(int k = 0; k < 4; k++){
      float lv = ((&h4.x)[k] - mean)*rstd*(&w4.x)[k] + (&b4.x)[k];
      const float* wrow = w1T + (size_t)(e4 + k)*512 + 4*l;
      float4 wlo = *(const float4*)(wrow);
      float4 whi = *(const float4*)(wrow + 256);
      #pragma unroll
      for(int i = 0; i < 4; i++){
        acc[i]   = fmaf((&wlo.x)[i], lv, acc[i]);
        acc[4+i] = fmaf((&whi.x)[i], lv, acc[4+i]);
      }
    }
  }
  float4 b1lo = *(const float4*)(b1 + 4*l);
  float4 b1hi = *(const float4*)(b1 + 256 + 4*l);
  float4 r0, r1;
  #pragma unroll
  for(int i = 0; i < 4; i++){
    (&r0.x)[i] = fmaxf(acc[i]   + (&b1lo.x)[i], 0.0f);
    (&r1.x)[i] = fmaxf(acc[4+i] + (&b1hi.x)[i], 0.0f);
  }
  *(float4*)(&h1s[wv*512 + 4*l])       = r0;
  *(float4*)(&h1s[wv*512 + 256 + 4*l]) = r1;
  __syncthreads();

  float o0 = 0, o1 = 0, o2 = 0, o3 = 0;
  for(int j4 = 0; j4 < 512; j4 += 4){
    float4 hj = *(const float4*)(&h1s[wv*512 + j4]);
    #pragma unroll
    for(int k = 0; k < 4; k++){
      const float* wrow = w2T + (size_t)(j4 + k)*256 + 4*l;
      float4 w4 = *(const float4*)wrow;
      float hk = (&hj.x)[k];
      o0 = fmaf(w4.x, hk, o0);
      o1 = fmaf(w4.y, hk, o1);
      o2 = fmaf(w4.z, hk, o2);
      o3 = fmaf(w4.w, hk, o3);
    }
  }
  float4 b2v = *(const float4*)(b2 + 4*l);
  float4 res;
  res.x = hv.x + b2v.x + o0;
  res.y = hv.y + b2v.y + o1;
  res.z = hv.z + b2v.z + o2;
  res.w = hv.w + b2v.w + o3;
  *(float4*)(slots + (size_t)row*256 + 4*l) = res;
}

extern "C" void kernel_launch(void* const* d_in, const int* in_sizes, int n_in,
                              void* d_out, int out_size, void* d_ws, size_t ws_size,
                              hipStream_t stream){
  const float* inputs = (const float*)d_in[0];
  const float* noise  = (const float*)d_in[1];
  const float* ln_in_w = (const float*)d_in[2];
  const float* ln_in_b = (const float*)d_in[3];
  const float* ln_sl_w = (const float*)d_in[4];
  const float* ln_sl_b = (const float*)d_in[5];
  const float* ln_ml_w = (const float*)d_in[6];
  const float* ln_ml_b = (const float*)d_in[7];
  const float* mu   = (const float*)d_in[8];
  const float* lsig = (const float*)d_in[9];
  const float* Wq  = (const float*)d_in[10];
  const float* Wk  = (const float*)d_in[11];
  const float* Wv  = (const float*)d_in[12];
  const float* wih = (const float*)d_in[13];
  const float* whh = (const float*)d_in[14];
  const float* bih = (const float*)d_in[15];
  const float* bhh = (const float*)d_in[16];
  const float* w1  = (const float*)d_in[17];
  const float* b1  = (const float*)d_in[18];
  const float* w2  = (const float*)d_in[19];
  const float* b2  = (const float*)d_in[20];

  char* ws = (char*)d_ws;
  size_t off = 0;
  unsigned short* x = (unsigned short*)(ws + off); off += (size_t)CB*CN*CD*2;   // 134217728
  float* slots = (float*)(ws + off); off += (size_t)CB*CS*CD*4;                 // 524288
  float* hp    = (float*)(ws + off); off += (size_t)CB*CS*CD*4;
  float* U     = (float*)(ws + off); off += (size_t)CB*CS*CD*4;
  float* den   = (float*)(ws + off); off += (size_t)CB*CS*4;                    // contiguous with U
  unsigned short* qt  = (unsigned short*)(ws + off); off += (size_t)CB*16*CD*2;
  unsigned short* M1T = (unsigned short*)(ws + off); off += (size_t)CD*CD*2;
  float* MihT = (float*)(ws + off); off += (size_t)CD*768*4;
  float* WhhT = (float*)(ws + off); off += (size_t)CD*768*4;
  float* w1T  = (float*)(ws + off); off += (size_t)CD*CH*4;
  float* w2T  = (float*)(ws + off); off += (size_t)CH*CD*4;

  k_ln<<<4096, 256, 0, stream>>>(inputs, ln_in_w, ln_in_b, x);
  k_slots0<<<512, 256, 0, stream>>>(noise, mu, lsig, slots);
  k_m1t<<<256, 256, 0, stream>>>(Wq, Wk, M1T);
  k_miht<<<768, 256, 0, stream>>>(wih, Wv, MihT);
  k_tr<<<768, 256, 0, stream>>>(whh, WhhT);
  k_tr<<<512, 256, 0, stream>>>(w1, w1T);
  k_tr<<<256, 512, 0, stream>>>(w2, w2T);

  for(int it = 0; it < 3; it++){
    k_qt<<<64, 256, 0, stream>>>(slots, ln_sl_w, ln_sl_b, M1T, qt);
    hipMemsetAsync(U, 0, ((size_t)CB*CS*CD + (size_t)CB*CS)*4, stream);
    k_attn<<<512, 256, 0, stream>>>(x, qt, U, den);
    k_gru<<<128, 256, 0, stream>>>(U, den, slots, MihT, WhhT, bih, bhh, hp);
    k_mlp<<<128, 256, 0, stream>>>(hp, ln_ml_w, ln_ml_b, w1T, b1, w2T, b2, slots);
  }
  hipMemcpyAsync(d_out, slots, (size_t)CB*CS*CD*4, hipMemcpyDeviceToDevice, stream);
}

// Round 2
// 826.702 us; speedup vs baseline: 1.2426x; 1.2426x over previous
//
#include <hip/hip_runtime.h>

#define CB 64
#define CN 4096
#define CD 256
#define CS 8
#define CH 512

typedef __bf16 bf16_t;
typedef bf16_t bf16x8 __attribute__((ext_vector_type(8)));
typedef float f32x4 __attribute__((ext_vector_type(4)));

__device__ __forceinline__ unsigned short f2bf(float f){
  unsigned int u = __builtin_bit_cast(unsigned int, f);
  u += 0x7FFFu + ((u >> 16) & 1u);
  return (unsigned short)(u >> 16);
}

__device__ __forceinline__ f32x4 mfma16(bf16x8 a, bf16x8 b, f32x4 c){
  return __builtin_amdgcn_mfma_f32_16x16x32_bf16(a, b, c, 0, 0, 0);
}

__device__ __forceinline__ void gl_lds16(const void* g, void* l){
  __builtin_amdgcn_global_load_lds(
      (const __attribute__((address_space(1))) unsigned int*)g,
      (__attribute__((address_space(3))) unsigned int*)l, 16, 0, 0);
}

// ---------------- LN over inputs -> x (bf16, row-major) ----------------
__global__ __launch_bounds__(256) void k_ln(const float* __restrict__ in,
    const float* __restrict__ gw, const float* __restrict__ gb,
    unsigned short* __restrict__ x){
  int blk = blockIdx.x;            // 4096 = 64 b * 64 ntiles
  int b = blk >> 6, nt = blk & 63;
  int wv = threadIdx.x >> 6, l = threadIdx.x & 63;
  const float* base = in + ((size_t)b*CN + (size_t)nt*64) * CD;
  unsigned short* xb = x + ((size_t)b*CN + (size_t)nt*64) * CD;
  float4 w4 = *(const float4*)(gw + 4*l);
  float4 b4 = *(const float4*)(gb + 4*l);
  for(int i = 0; i < 16; i++){
    int r = wv*16 + i;
    float4 v = *(const float4*)(base + (size_t)r*CD + 4*l);
    float s1 = v.x + v.y + v.z + v.w;
    float s2 = v.x*v.x + v.y*v.y + v.z*v.z + v.w*v.w;
    #pragma unroll
    for(int m = 1; m < 64; m <<= 1){ s1 += __shfl_xor(s1, m); s2 += __shfl_xor(s2, m); }
    float mean = s1 * (1.0f/CD);
    float var  = fmaxf(s2 * (1.0f/CD) - mean*mean, 0.0f);
    float rstd = rsqrtf(var + 1e-5f);
    float y0 = (v.x - mean)*rstd*w4.x + b4.x;
    float y1 = (v.y - mean)*rstd*w4.y + b4.y;
    float y2 = (v.z - mean)*rstd*w4.z + b4.z;
    float y3 = (v.w - mean)*rstd*w4.w + b4.w;
    uint2 p;
    p.x = (unsigned)f2bf(y0) | ((unsigned)f2bf(y1) << 16);
    p.y = (unsigned)f2bf(y2) | ((unsigned)f2bf(y3) << 16);
    *(uint2*)(xb + (size_t)r*CD + 4*l) = p;
  }
}

// ---------------- slots init ----------------
__global__ __launch_bounds__(256) void k_slots0(const float* __restrict__ noise,
    const float* __restrict__ mu, const float* __restrict__ lsig, float* __restrict__ slots){
  int i = blockIdx.x*256 + threadIdx.x;   // 131072
  int d = i & 255;
  slots[i] = mu[d] + __expf(lsig[d]) * noise[i];
}

// ---------------- M1T[ep][e] = scale * sum_d Wq[d][e]*Wk[d][ep]  (bf16) ----------------
__global__ __launch_bounds__(256) void k_m1t(const float* __restrict__ Wq,
    const float* __restrict__ Wk, unsigned short* __restrict__ M1T){
  int ep = blockIdx.x, e = threadIdx.x;
  float acc = 0.0f;
  for(int d = 0; d < 256; d++) acc = fmaf(Wq[(size_t)d*256 + e], Wk[(size_t)d*256 + ep], acc);
  M1T[(size_t)ep*256 + e] = f2bf(acc * 0.0625f);
}

// ---------------- MihT[e][j] = sum_d wih[j][d]*Wv[d][e]  (fp32) ----------------
__global__ __launch_bounds__(256) void k_miht(const float* __restrict__ wih,
    const float* __restrict__ Wv, float* __restrict__ MihT){
  int j = blockIdx.x, e = threadIdx.x;
  float acc = 0.0f;
  for(int d = 0; d < 256; d++) acc = fmaf(wih[(size_t)j*256 + d], Wv[(size_t)d*256 + e], acc);
  MihT[(size_t)e*768 + j] = acc;
}

// ---------------- generic transpose: dst[c][r] = src[r][c] ----------------
__global__ void k_tr(const float* __restrict__ src, float* __restrict__ dst){
  int r = blockIdx.x, c = threadIdx.x;
  int R = gridDim.x, C = blockDim.x;
  dst[(size_t)c*R + r] = src[(size_t)r*C + c];
}

// ---------------- qt[b][s][ep] = scale * LN(slots) @ M1   (bf16, rows 8..15 zero) ----------------
__global__ __launch_bounds__(256) void k_qt(const float* __restrict__ slots,
    const float* __restrict__ lw, const float* __restrict__ lb,
    const unsigned short* __restrict__ M1T, unsigned short* __restrict__ qt){
  __shared__ unsigned short sn[16*264];
  int b = blockIdx.x;
  int wv = threadIdx.x >> 6, l = threadIdx.x & 63;
  int lm = l & 15, lg = l >> 4;
  float4 w4 = *(const float4*)(lw + 4*l);
  float4 b4 = *(const float4*)(lb + 4*l);
  for(int i = 0; i < 2; i++){
    int r = wv*2 + i;
    float4 v = *(const float4*)(slots + ((size_t)b*CS + r)*CD + 4*l);
    float s1 = v.x + v.y + v.z + v.w;
    float s2 = v.x*v.x + v.y*v.y + v.z*v.z + v.w*v.w;
    #pragma unroll
    for(int m = 1; m < 64; m <<= 1){ s1 += __shfl_xor(s1, m); s2 += __shfl_xor(s2, m); }
    float mean = s1 * (1.0f/CD);
    float var  = fmaxf(s2 * (1.0f/CD) - mean*mean, 0.0f);
    float rstd = rsqrtf(var + 1e-5f);
    float y0 = (v.x - mean)*rstd*w4.x + b4.x;
    float y1 = (v.y - mean)*rstd*w4.y + b4.y;
    float y2 = (v.z - mean)*rstd*w4.z + b4.z;
    float y3 = (v.w - mean)*rstd*w4.w + b4.w;
    uint2 p;
    p.x = (unsigned)f2bf(y0) | ((unsigned)f2bf(y1) << 16);
    p.y = (unsigned)f2bf(y2) | ((unsigned)f2bf(y3) << 16);
    *(uint2*)(&sn[r*264 + 4*l]) = p;
    uint2 z; z.x = 0u; z.y = 0u;
    *(uint2*)(&sn[(r+8)*264 + 4*l]) = z;
  }
  __syncthreads();
  bf16x8 af[8];
  #pragma unroll
  for(int k = 0; k < 8; k++) af[k] = *(const bf16x8*)(&sn[lm*264 + k*32 + lg*8]);
  #pragma unroll
  for(int ntile = 0; ntile < 4; ntile++){
    int ep = wv*64 + ntile*16 + lm;
    f32x4 acc = {0.f, 0.f, 0.f, 0.f};
    const unsigned short* mrow = M1T + (size_t)ep*CD;
    #pragma unroll
    for(int k = 0; k < 8; k++){
      bf16x8 bf = *(const bf16x8*)(mrow + k*32 + lg*8);
      acc = mfma16(af[k], bf, acc);
    }
    #pragma unroll
    for(int reg = 0; reg < 4; reg++){
      int s = lg*4 + reg;
      qt[((size_t)b*16 + s)*CD + ep] = f2bf(acc[reg]);
    }
  }
}

// ---------------- fused attention pass: logits -> softmax+eps -> U,den ----------------
__global__ __launch_bounds__(256) void k_attn(const unsigned short* __restrict__ x,
    const unsigned short* __restrict__ qt, float* __restrict__ U, float* __restrict__ den){
  __shared__ unsigned short xt[64*256];   // XOR-swizzled 16B chunks
  __shared__ unsigned short pt[16*72];    // P^T (slot-major), padded stride
  int b = blockIdx.x >> 3, chunk = blockIdx.x & 7;
  int wv = threadIdx.x >> 6, l = threadIdx.x & 63;
  int lm = l & 15, lg = l >> 4;

  // persistent qt B-fragments
  bf16x8 qb[8];
  const unsigned short* qrow = qt + ((size_t)b*16 + lm)*CD;
  #pragma unroll
  for(int k = 0; k < 8; k++) qb[k] = *(const bf16x8*)(qrow + k*32 + lg*8);

  f32x4 uacc[4];
  #pragma unroll
  for(int nt = 0; nt < 4; nt++){ f32x4 z = {0.f,0.f,0.f,0.f}; uacc[nt] = z; }
  float dacc = 0.0f;

  const unsigned short* xbatch = x + (size_t)b*CN*CD + (size_t)chunk*512*CD;

  for(int t = 0; t < 8; t++){
    const unsigned short* xtile = xbatch + (size_t)t*64*CD;
    __syncthreads();   // previous phase2 done before restaging
    #pragma unroll
    for(int k2 = 0; k2 < 8; k2++){
      int r0 = wv*16 + k2*2;
      int row = r0 + (l >> 5);
      int c = l & 31;
      int f = (row >> 3) & 3;
      const unsigned short* g = xtile + (size_t)row*CD + (size_t)(c ^ f)*8;
      gl_lds16(g, &xt[r0*CD]);
    }
    __syncthreads();   // staging complete

    // phase 1: logits for this wave's 16 rows
    f32x4 c4 = {0.f, 0.f, 0.f, 0.f};
    int rowl = wv*16 + lm;
    int f1 = (rowl >> 3) & 3;
    #pragma unroll
    for(int k = 0; k < 8; k++){
      int cc = (k*4 + lg) ^ f1;
      bf16x8 a = *(const bf16x8*)(&xt[rowl*256 + cc*8]);
      c4 = mfma16(a, qb[k], c4);
    }
    // softmax over slots (lane's slot = lm, 4 rows in regs)
    float pv[4];
    #pragma unroll
    for(int reg = 0; reg < 4; reg++){
      float v = (lm < 8) ? c4[reg] : -1e30f;
      float mx = v;
      #pragma unroll
      for(int m = 1; m < 16; m <<= 1) mx = fmaxf(mx, __shfl_xor(mx, m));
      float e = __expf(v - mx);
      float s = e;
      #pragma unroll
      for(int m = 1; m < 16; m <<= 1) s += __shfl_xor(s, m);
      float p = (lm < 8) ? (e/s + 1e-8f) : 0.0f;
      dacc += p;
      pv[reg] = p;
    }
    int rbase = wv*16 + lg*4;
    unsigned int p01 = (unsigned)f2bf(pv[0]) | ((unsigned)f2bf(pv[1]) << 16);
    unsigned int p23 = (unsigned)f2bf(pv[2]) | ((unsigned)f2bf(pv[3]) << 16);
    *(unsigned int*)(&pt[lm*72 + rbase])     = p01;
    *(unsigned int*)(&pt[lm*72 + rbase + 2]) = p23;
    __syncthreads();   // PT ready

    // phase 2: U[s, e-slice] += P^T @ X  (wave covers 64 dims)
    #pragma unroll
    for(int ks = 0; ks < 2; ks++){
      bf16x8 a = *(const bf16x8*)(&pt[lm*72 + ks*32 + lg*8]);
      int rb = ks*32 + lg*8;
      int f2 = (rb >> 3) & 3;
      #pragma unroll
      for(int nt = 0; nt < 4; nt++){
        int e = wv*64 + nt*16 + lm;
        int cidx = ((e >> 3) ^ f2);
        bf16x8 bfr;
        #pragma unroll
        for(int j = 0; j < 8; j++){
          unsigned short tv = xt[(rb + j)*256 + cidx*8 + (e & 7)];
          bfr[j] = __builtin_bit_cast(bf16_t, tv);
        }
        uacc[nt] = mfma16(a, bfr, uacc[nt]);
      }
    }
  }

  // epilogue
  dacc += __shfl_xor(dacc, 16);
  dacc += __shfl_xor(dacc, 32);
  if(l < 8) atomicAdd(&den[b*CS + l], dacc);
  if(lg < 2){
    #pragma unroll
    for(int nt = 0; nt < 4; nt++){
      #pragma unroll
      for(int reg = 0; reg < 4; reg++){
        int s = lg*4 + reg;
        atomicAdd(&U[((size_t)b*CS + s)*CD + wv*64 + nt*16 + lm], uacc[nt][reg]);
      }
    }
  }
}

// ---------------- tiled fp32 GEMM: C = A@B (+epilogue), NT=64 cols/tile ----------------
// EPI 0: plain store. EPI 1: relu(acc + bias[n]). EPI 2: acc + bias[n] + res[m][n].
template<int MT, int TM, int EPI>
__global__ __launch_bounds__(256) void k_gemm(
    const float* __restrict__ A, int lda, const float* __restrict__ B, int ldb,
    float* __restrict__ C, int ldc, int K, int ntn,
    const float* __restrict__ bias, const float* __restrict__ res,
    const float* __restrict__ A2, const float* __restrict__ B2, float* __restrict__ C2){
  __shared__ float AsT[32*(MT+1)];
  __shared__ float Bs[32*68];
  if(blockIdx.y == 1){ A = A2; B = B2; C = C2; }
  int bm = blockIdx.x / ntn, bn = blockIdx.x % ntn;
  int m0 = bm*MT, n0 = bn*64;
  int tid = threadIdx.x;
  int tx = tid & 15, ty = tid >> 4;
  float acc[TM][4];
  #pragma unroll
  for(int i = 0; i < TM; i++)
    #pragma unroll
    for(int j = 0; j < 4; j++) acc[i][j] = 0.0f;

  for(int k0 = 0; k0 < K; k0 += 32){
    __syncthreads();
    #pragma unroll
    for(int v = 0; v < MT/32; v++){
      int idx = v*256 + tid;
      int ar = idx >> 3, ac = (idx & 7)*4;
      float4 a4 = *(const float4*)(A + (size_t)(m0+ar)*lda + k0 + ac);
      AsT[(ac+0)*(MT+1) + ar] = a4.x;
      AsT[(ac+1)*(MT+1) + ar] = a4.y;
      AsT[(ac+2)*(MT+1) + ar] = a4.z;
      AsT[(ac+3)*(MT+1) + ar] = a4.w;
    }
    #pragma unroll
    for(int v = 0; v < 2; v++){
      int idx = v*256 + tid;
      int kr = idx >> 4, c4 = (idx & 15)*4;
      *(float4*)(&Bs[kr*68 + c4]) = *(const float4*)(B + (size_t)(k0+kr)*ldb + n0 + c4);
    }
    __syncthreads();
    #pragma unroll
    for(int k = 0; k < 32; k++){
      float av[TM];
      #pragma unroll
      for(int i = 0; i < TM; i++) av[i] = AsT[k*(MT+1) + ty*TM + i];
      float4 bv = *(const float4*)(&Bs[k*68 + tx*4]);
      #pragma unroll
      for(int i = 0; i < TM; i++){
        acc[i][0] = fmaf(av[i], bv.x, acc[i][0]);
        acc[i][1] = fmaf(av[i], bv.y, acc[i][1]);
        acc[i][2] = fmaf(av[i], bv.z, acc[i][2]);
        acc[i][3] = fmaf(av[i], bv.w, acc[i][3]);
      }
    }
  }
  int n = n0 + tx*4;
  float4 bi;
  if(EPI != 0) bi = *(const float4*)(bias + n);
  #pragma unroll
  for(int i = 0; i < TM; i++){
    int m = m0 + ty*TM + i;
    float4 o;
    if(EPI == 0){
      o.x = acc[i][0]; o.y = acc[i][1]; o.z = acc[i][2]; o.w = acc[i][3];
    } else if(EPI == 1){
      o.x = fmaxf(acc[i][0] + bi.x, 0.0f);
      o.y = fmaxf(acc[i][1] + bi.y, 0.0f);
      o.z = fmaxf(acc[i][2] + bi.z, 0.0f);
      o.w = fmaxf(acc[i][3] + bi.w, 0.0f);
    } else {
      float4 rv = *(const float4*)(res + (size_t)m*ldc + n);
      o.x = acc[i][0] + bi.x + rv.x;
      o.y = acc[i][1] + bi.y + rv.y;
      o.z = acc[i][2] + bi.z + rv.z;
      o.w = acc[i][3] + bi.w + rv.w;
    }
    *(float4*)(C + (size_t)m*ldc + n) = o;
  }
}

// ---------------- GRU gate activations + LN(mlp) prep; wave per row ----------------
__global__ __launch_bounds__(256) void k_act(const float* __restrict__ gi,
    const float* __restrict__ gh, const float* __restrict__ den,
    const float* __restrict__ slots, const float* __restrict__ bih,
    const float* __restrict__ bhh, const float* __restrict__ lw,
    const float* __restrict__ lb, float* __restrict__ hp, float* __restrict__ lnh){
  int wv = threadIdx.x >> 6, l = threadIdx.x & 63;
  int row = blockIdx.x*4 + wv;
  const float* gir = gi + (size_t)row*768;
  const float* ghr = gh + (size_t)row*768;
  float invd = 1.0f / den[row];
  float4 air = *(const float4*)(gir + 4*l);
  float4 aiz = *(const float4*)(gir + 256 + 4*l);
  float4 ain = *(const float4*)(gir + 512 + 4*l);
  float4 ahr = *(const float4*)(ghr + 4*l);
  float4 ahz = *(const float4*)(ghr + 256 + 4*l);
  float4 ahn = *(const float4*)(ghr + 512 + 4*l);
  float4 br = *(const float4*)(bih + 4*l);
  float4 bz = *(const float4*)(bih + 256 + 4*l);
  float4 bn = *(const float4*)(bih + 512 + 4*l);
  float4 cr = *(const float4*)(bhh + 4*l);
  float4 cz = *(const float4*)(bhh + 256 + 4*l);
  float4 cn = *(const float4*)(bhh + 512 + 4*l);
  float4 hc = *(const float4*)(slots + (size_t)row*256 + 4*l);
  float4 h;
  #pragma unroll
  for(int i = 0; i < 4; i++){
    float gr = (&air.x)[i]*invd + (&br.x)[i] + (&ahr.x)[i] + (&cr.x)[i];
    float gz = (&aiz.x)[i]*invd + (&bz.x)[i] + (&ahz.x)[i] + (&cz.x)[i];
    float gn = (&ain.x)[i]*invd + (&bn.x)[i];
    float hn = (&ahn.x)[i] + (&cn.x)[i];
    float r = 1.0f/(1.0f + __expf(-gr));
    float z = 1.0f/(1.0f + __expf(-gz));
    float n = tanhf(gn + r*hn);
    (&h.x)[i] = (1.0f - z)*n + z*(&hc.x)[i];
  }
  *(float4*)(hp + (size_t)row*256 + 4*l) = h;
  float s1 = h.x + h.y + h.z + h.w;
  float s2 = h.x*h.x + h.y*h.y + h.z*h.z + h.w*h.w;
  #pragma unroll
  for(int m = 1; m < 64; m <<= 1){ s1 += __shfl_xor(s1, m); s2 += __shfl_xor(s2, m); }
  float mean = s1 * (1.0f/CD);
  float var  = fmaxf(s2 * (1.0f/CD) - mean*mean, 0.0f);
  float rstd = rsqrtf(var + 1e-5f);
  float4 w4 = *(const float4*)(lw + 4*l);
  float4 b4 = *(const float4*)(lb + 4*l);
  float4 o;
  o.x = (h.x - mean)*rstd*w4.x + b4.x;
  o.y = (h.y - mean)*rstd*w4.y + b4.y;
  o.z = (h.z - mean)*rstd*w4.z + b4.z;
  o.w = (h.w - mean)*rstd*w4.w + b4.w;
  *(float4*)(lnh + (size_t)row*256 + 4*l) = o;
}

extern "C" void kernel_launch(void* const* d_in, const int* in_sizes, int n_in,
                              void* d_out, int out_size, void* d_ws, size_t ws_size,
                              hipStream_t stream){
  const float* inputs = (const float*)d_in[0];
  const float* noise  = (const float*)d_in[1];
  const float* ln_in_w = (const float*)d_in[2];
  const float* ln_in_b = (const float*)d_in[3];
  const float* ln_sl_w = (const float*)d_in[4];
  const float* ln_sl_b = (const float*)d_in[5];
  const float* ln_ml_w = (const float*)d_in[6];
  const float* ln_ml_b = (const float*)d_in[7];
  const float* mu   = (const float*)d_in[8];
  const float* lsig = (const float*)d_in[9];
  const float* Wq  = (const float*)d_in[10];
  const float* Wk  = (const float*)d_in[11];
  const float* Wv  = (const float*)d_in[12];
  const float* wih = (const float*)d_in[13];
  const float* whh = (const float*)d_in[14];
  const float* bih = (const float*)d_in[15];
  const float* bhh = (const float*)d_in[16];
  const float* w1  = (const float*)d_in[17];
  const float* b1  = (const float*)d_in[18];
  const float* w2  = (const float*)d_in[19];
  const float* b2  = (const float*)d_in[20];

  char* ws = (char*)d_ws;
  size_t off = 0;
  unsigned short* x = (unsigned short*)(ws + off); off += (size_t)CB*CN*CD*2;
  float* slots = (float*)(ws + off); off += (size_t)CB*CS*CD*4;
  float* hp    = (float*)(ws + off); off += (size_t)CB*CS*CD*4;
  float* U     = (float*)(ws + off); off += (size_t)CB*CS*CD*4;
  float* den   = (float*)(ws + off); off += (size_t)CB*CS*4;
  unsigned short* qt  = (unsigned short*)(ws + off); off += (size_t)CB*16*CD*2;
  unsigned short* M1T = (unsigned short*)(ws + off); off += (size_t)CD*CD*2;
  float* MihT = (float*)(ws + off); off += (size_t)CD*768*4;
  float* WhhT = (float*)(ws + off); off += (size_t)CD*768*4;
  float* w1T  = (float*)(ws + off); off += (size_t)CD*CH*4;
  float* w2T  = (float*)(ws + off); off += (size_t)CH*CD*4;
  float* gi   = (float*)(ws + off); off += (size_t)512*768*4;
  float* gh   = (float*)(ws + off); off += (size_t)512*768*4;
  float* lnh  = (float*)(ws + off); off += (size_t)512*256*4;
  float* h1   = (float*)(ws + off); off += (size_t)512*512*4;

  k_ln<<<4096, 256, 0, stream>>>(inputs, ln_in_w, ln_in_b, x);
  k_slots0<<<512, 256, 0, stream>>>(noise, mu, lsig, slots);
  k_m1t<<<256, 256, 0, stream>>>(Wq, Wk, M1T);
  k_miht<<<768, 256, 0, stream>>>(wih, Wv, MihT);
  k_tr<<<768, 256, 0, stream>>>(whh, WhhT);
  k_tr<<<512, 256, 0, stream>>>(w1, w1T);
  k_tr<<<256, 512, 0, stream>>>(w2, w2T);

  for(int it = 0; it < 3; it++){
    k_qt<<<64, 256, 0, stream>>>(slots, ln_sl_w, ln_sl_b, M1T, qt);
    hipMemsetAsync(U, 0, ((size_t)CB*CS*CD + (size_t)CB*CS)*4, stream);
    k_attn<<<512, 256, 0, stream>>>(x, qt, U, den);
    // gates: gi = U @ MihT [512x768], gh = slots @ WhhT [512x768]
    k_gemm<64, 4, 0><<<dim3(96, 2), 256, 0, stream>>>(
        U, 256, MihT, 768, gi, 768, 256, 12, nullptr, nullptr,
        slots, WhhT, gh);
    k_act<<<128, 256, 0, stream>>>(gi, gh, den, slots, bih, bhh, ln_ml_w, ln_ml_b, hp, lnh);
    // h1 = relu(lnh @ w1T + b1)  [512x512]
    k_gemm<64, 4, 1><<<dim3(64, 1), 256, 0, stream>>>(
        lnh, 256, w1T, 512, h1, 512, 256, 8, b1, nullptr,
        nullptr, nullptr, nullptr);
    // slots = h1 @ w2T + b2 + hp  [512x256]
    k_gemm<32, 2, 2><<<dim3(64, 1), 256, 0, stream>>>(
        h1, 512, w2T, 256, slots, 256, 512, 4, b2, hp,
        nullptr, nullptr, nullptr);
  }
  hipMemcpyAsync(d_out, slots, (size_t)CB*CS*CD*4, hipMemcpyDeviceToDevice, stream);
}

// Round 3
// 805.026 us; speedup vs baseline: 1.2761x; 1.0269x over previous
//
#include <hip/hip_runtime.h>

#define CB 64
#define CN 4096
#define CD 256
#define CS 8
#define CH 512

typedef __bf16 bf16_t;
typedef bf16_t bf16x8 __attribute__((ext_vector_type(8)));
typedef float f32x4 __attribute__((ext_vector_type(4)));

__device__ __forceinline__ unsigned short f2bf(float f){
  unsigned int u = __builtin_bit_cast(unsigned int, f);
  u += 0x7FFFu + ((u >> 16) & 1u);
  return (unsigned short)(u >> 16);
}

__device__ __forceinline__ f32x4 mfma16(bf16x8 a, bf16x8 b, f32x4 c){
  return __builtin_amdgcn_mfma_f32_16x16x32_bf16(a, b, c, 0, 0, 0);
}

__device__ __forceinline__ void gl_lds16(const void* g, void* l){
  __builtin_amdgcn_global_load_lds(
      (const __attribute__((address_space(1))) unsigned int*)g,
      (__attribute__((address_space(3))) unsigned int*)l, 16, 0, 0);
}

// ---------------- LN over inputs -> x (bf16, row-major) ----------------
__global__ __launch_bounds__(256) void k_ln(const float* __restrict__ in,
    const float* __restrict__ gw, const float* __restrict__ gb,
    unsigned short* __restrict__ x){
  int blk = blockIdx.x;            // 4096 = 64 b * 64 ntiles
  int b = blk >> 6, nt = blk & 63;
  int wv = threadIdx.x >> 6, l = threadIdx.x & 63;
  const float* base = in + ((size_t)b*CN + (size_t)nt*64) * CD;
  unsigned short* xb = x + ((size_t)b*CN + (size_t)nt*64) * CD;
  float4 w4 = *(const float4*)(gw + 4*l);
  float4 b4 = *(const float4*)(gb + 4*l);
  for(int i = 0; i < 16; i++){
    int r = wv*16 + i;
    float4 v = *(const float4*)(base + (size_t)r*CD + 4*l);
    float s1 = v.x + v.y + v.z + v.w;
    float s2 = v.x*v.x + v.y*v.y + v.z*v.z + v.w*v.w;
    #pragma unroll
    for(int m = 1; m < 64; m <<= 1){ s1 += __shfl_xor(s1, m); s2 += __shfl_xor(s2, m); }
    float mean = s1 * (1.0f/CD);
    float var  = fmaxf(s2 * (1.0f/CD) - mean*mean, 0.0f);
    float rstd = rsqrtf(var + 1e-5f);
    float y0 = (v.x - mean)*rstd*w4.x + b4.x;
    float y1 = (v.y - mean)*rstd*w4.y + b4.y;
    float y2 = (v.z - mean)*rstd*w4.z + b4.z;
    float y3 = (v.w - mean)*rstd*w4.w + b4.w;
    uint2 p;
    p.x = (unsigned)f2bf(y0) | ((unsigned)f2bf(y1) << 16);
    p.y = (unsigned)f2bf(y2) | ((unsigned)f2bf(y3) << 16);
    *(uint2*)(xb + (size_t)r*CD + 4*l) = p;
  }
}

// ---------------- fused setup: M1T, MihT, WhhT, w1T, w2T, slots init ----------------
__global__ __launch_bounds__(256) void k_setup(
    const float* __restrict__ Wq, const float* __restrict__ Wk,
    const float* __restrict__ wih, const float* __restrict__ Wv,
    const float* __restrict__ whh, const float* __restrict__ w1,
    const float* __restrict__ w2, const float* __restrict__ noise,
    const float* __restrict__ mu, const float* __restrict__ lsig,
    unsigned short* __restrict__ M1T, float* __restrict__ MihT,
    float* __restrict__ WhhT, float* __restrict__ w1T,
    float* __restrict__ w2T, float* __restrict__ slots){
  int bid = blockIdx.x, tid = threadIdx.x;
  if(bid < 256){                       // M1T[ep][e] = scale * sum_d Wq[d][e]*Wk[d][ep]
    int ep = bid, e = tid;
    float acc = 0.0f;
    for(int d = 0; d < 256; d++) acc = fmaf(Wq[(size_t)d*256 + e], Wk[(size_t)d*256 + ep], acc);
    M1T[(size_t)ep*256 + e] = f2bf(acc * 0.0625f);
  } else if(bid < 1024){               // MihT[e][j] = sum_d wih[j][d]*Wv[d][e]
    int j = bid - 256, e = tid;
    float acc = 0.0f;
    for(int d = 0; d < 256; d++) acc = fmaf(wih[(size_t)j*256 + d], Wv[(size_t)d*256 + e], acc);
    MihT[(size_t)e*768 + j] = acc;
  } else if(bid < 1792){               // WhhT[c][r] = whh[r][c], 768x256
    int r = bid - 1024, c = tid;
    WhhT[(size_t)c*768 + r] = whh[(size_t)r*256 + c];
  } else if(bid < 2304){               // w1T[c][r] = w1[r][c], 512x256
    int r = bid - 1792, c = tid;
    w1T[(size_t)c*512 + r] = w1[(size_t)r*256 + c];
  } else if(bid < 2816){               // w2T[c][r] = w2[r][c], 256x512
    int idx = (bid - 2304)*256 + tid;
    int r = idx >> 9, c = idx & 511;
    w2T[(size_t)c*256 + r] = w2[(size_t)r*512 + c];
  } else {                             // slots init, 131072 elems
    int idx = (bid - 2816)*256 + tid;
    int d = idx & 255;
    slots[idx] = mu[d] + __expf(lsig[d]) * noise[idx];
  }
}

// ---------------- qt = scale*LN(slots)@M1 (bf16, rows 8..15 zero); also zeros U,den ----------------
__global__ __launch_bounds__(256) void k_qt(const float* __restrict__ slots,
    const float* __restrict__ lw, const float* __restrict__ lb,
    const unsigned short* __restrict__ M1T, unsigned short* __restrict__ qt,
    float* __restrict__ U, float* __restrict__ den){
  __shared__ unsigned short sn[16*264];
  int b = blockIdx.x;
  int tid = threadIdx.x;
  // zero this batch's U slice + den (attn accumulates atomically)
  float4 z4 = {0.f, 0.f, 0.f, 0.f};
  float* Ub = U + (size_t)b*CS*CD;
  *(float4*)(Ub + tid*8)     = z4;
  *(float4*)(Ub + tid*8 + 4) = z4;
  if(tid < CS) den[b*CS + tid] = 0.0f;

  int wv = tid >> 6, l = tid & 63;
  int lm = l & 15, lg = l >> 4;
  float4 w4 = *(const float4*)(lw + 4*l);
  float4 b4 = *(const float4*)(lb + 4*l);
  for(int i = 0; i < 2; i++){
    int r = wv*2 + i;
    float4 v = *(const float4*)(slots + ((size_t)b*CS + r)*CD + 4*l);
    float s1 = v.x + v.y + v.z + v.w;
    float s2 = v.x*v.x + v.y*v.y + v.z*v.z + v.w*v.w;
    #pragma unroll
    for(int m = 1; m < 64; m <<= 1){ s1 += __shfl_xor(s1, m); s2 += __shfl_xor(s2, m); }
    float mean = s1 * (1.0f/CD);
    float var  = fmaxf(s2 * (1.0f/CD) - mean*mean, 0.0f);
    float rstd = rsqrtf(var + 1e-5f);
    float y0 = (v.x - mean)*rstd*w4.x + b4.x;
    float y1 = (v.y - mean)*rstd*w4.y + b4.y;
    float y2 = (v.z - mean)*rstd*w4.z + b4.z;
    float y3 = (v.w - mean)*rstd*w4.w + b4.w;
    uint2 p;
    p.x = (unsigned)f2bf(y0) | ((unsigned)f2bf(y1) << 16);
    p.y = (unsigned)f2bf(y2) | ((unsigned)f2bf(y3) << 16);
    *(uint2*)(&sn[r*264 + 4*l]) = p;
    uint2 zz; zz.x = 0u; zz.y = 0u;
    *(uint2*)(&sn[(r+8)*264 + 4*l]) = zz;
  }
  __syncthreads();
  bf16x8 af[8];
  #pragma unroll
  for(int k = 0; k < 8; k++) af[k] = *(const bf16x8*)(&sn[lm*264 + k*32 + lg*8]);
  #pragma unroll
  for(int ntile = 0; ntile < 4; ntile++){
    int ep = wv*64 + ntile*16 + lm;
    f32x4 acc = {0.f, 0.f, 0.f, 0.f};
    const unsigned short* mrow = M1T + (size_t)ep*CD;
    #pragma unroll
    for(int k = 0; k < 8; k++){
      bf16x8 bf = *(const bf16x8*)(mrow + k*32 + lg*8);
      acc = mfma16(af[k], bf, acc);
    }
    #pragma unroll
    for(int reg = 0; reg < 4; reg++){
      int s = lg*4 + reg;
      qt[((size_t)b*16 + s)*CD + ep] = f2bf(acc[reg]);
    }
  }
}

// ---------------- fused attention pass: logits -> softmax+eps -> U,den ----------------
// swizzle f(row) = (row ^ (row>>3)) & 7 : phase-1 b128 reads hit all 32 banks at the
// 8-dword/bank minimum; phase-2 u16 gather stays 2-way (free).
__global__ __launch_bounds__(256) void k_attn(const unsigned short* __restrict__ x,
    const unsigned short* __restrict__ qt, float* __restrict__ U, float* __restrict__ den){
  __shared__ unsigned short xt[64*256];
  __shared__ unsigned short pt[16*72];
  int b = blockIdx.x >> 4, chunk = blockIdx.x & 15;   // 16 chunks -> 1024 blocks, 4/CU
  int wv = threadIdx.x >> 6, l = threadIdx.x & 63;
  int lm = l & 15, lg = l >> 4;

  bf16x8 qb[8];
  const unsigned short* qrow = qt + ((size_t)b*16 + lm)*CD;
  #pragma unroll
  for(int k = 0; k < 8; k++) qb[k] = *(const bf16x8*)(qrow + k*32 + lg*8);

  f32x4 uacc[4];
  #pragma unroll
  for(int nt = 0; nt < 4; nt++){ f32x4 z = {0.f,0.f,0.f,0.f}; uacc[nt] = z; }
  float dacc = 0.0f;

  const unsigned short* xbatch = x + (size_t)b*CN*CD + (size_t)chunk*256*CD;

  for(int t = 0; t < 4; t++){
    const unsigned short* xtile = xbatch + (size_t)t*64*CD;
    __syncthreads();   // phase2 of previous tile done before restaging
    #pragma unroll
    for(int k2 = 0; k2 < 8; k2++){
      int r0 = wv*16 + k2*2;
      int row = r0 + (l >> 5);
      int c = l & 31;
      int f = (row ^ (row >> 3)) & 7;
      const unsigned short* g = xtile + (size_t)row*CD + (size_t)(c ^ f)*8;
      gl_lds16(g, &xt[r0*CD]);
    }
    __syncthreads();   // staging complete

    // phase 1: logits for this wave's 16 rows
    f32x4 c4 = {0.f, 0.f, 0.f, 0.f};
    int rowl = wv*16 + lm;
    int f1 = (rowl ^ (rowl >> 3)) & 7;
    #pragma unroll
    for(int k = 0; k < 8; k++){
      int cc = (k*4 + lg) ^ f1;
      bf16x8 a = *(const bf16x8*)(&xt[rowl*256 + cc*8]);
      c4 = mfma16(a, qb[k], c4);
    }
    // softmax over slots (lane's slot = lm, 4 rows in regs)
    float pv[4];
    #pragma unroll
    for(int reg = 0; reg < 4; reg++){
      float v = (lm < 8) ? c4[reg] : -1e30f;
      float mx = v;
      #pragma unroll
      for(int m = 1; m < 16; m <<= 1) mx = fmaxf(mx, __shfl_xor(mx, m));
      float e = __expf(v - mx);
      float s = e;
      #pragma unroll
      for(int m = 1; m < 16; m <<= 1) s += __shfl_xor(s, m);
      float p = (lm < 8) ? (e/s + 1e-8f) : 0.0f;
      dacc += p;
      pv[reg] = p;
    }
    int rbase = wv*16 + lg*4;
    unsigned int p01 = (unsigned)f2bf(pv[0]) | ((unsigned)f2bf(pv[1]) << 16);
    unsigned int p23 = (unsigned)f2bf(pv[2]) | ((unsigned)f2bf(pv[3]) << 16);
    *(unsigned int*)(&pt[lm*72 + rbase])     = p01;
    *(unsigned int*)(&pt[lm*72 + rbase + 2]) = p23;
    __syncthreads();   // PT ready

    // phase 2: U[s, e-slice] += P^T @ X  (wave covers 64 dims)
    #pragma unroll
    for(int ks = 0; ks < 2; ks++){
      bf16x8 a = *(const bf16x8*)(&pt[lm*72 + ks*32 + lg*8]);
      int rb = ks*32 + lg*8;
      #pragma unroll
      for(int nt = 0; nt < 4; nt++){
        int e = wv*64 + nt*16 + lm;
        bf16x8 bfr;
        #pragma unroll
        for(int j = 0; j < 8; j++){
          int row2 = rb + j;
          int f2 = (row2 ^ (row2 >> 3)) & 7;
          int cidx = (e >> 3) ^ f2;
          unsigned short tv = xt[row2*256 + cidx*8 + (e & 7)];
          bfr[j] = __builtin_bit_cast(bf16_t, tv);
        }
        uacc[nt] = mfma16(a, bfr, uacc[nt]);
      }
    }
  }

  // epilogue
  dacc += __shfl_xor(dacc, 16);
  dacc += __shfl_xor(dacc, 32);
  if(l < 8) atomicAdd(&den[b*CS + l], dacc);
  if(lg < 2){
    #pragma unroll
    for(int nt = 0; nt < 4; nt++){
      #pragma unroll
      for(int reg = 0; reg < 4; reg++){
        int s = lg*4 + reg;
        atomicAdd(&U[((size_t)b*CS + s)*CD + wv*64 + nt*16 + lm], uacc[nt][reg]);
      }
    }
  }
}

// ---------------- tiled fp32 GEMM: C = A@B (+epilogue), NT=64 cols/tile ----------------
// EPI 0: plain store. EPI 1: relu(acc + bias[n]). EPI 2: acc + bias[n] + res[m][n].
template<int MT, int TM, int EPI>
__global__ __launch_bounds__(256) void k_gemm(
    const float* __restrict__ A, int lda, const float* __restrict__ B, int ldb,
    float* __restrict__ C, int ldc, int K, int ntn,
    const float* __restrict__ bias, const float* __restrict__ res,
    const float* __restrict__ A2, const float* __restrict__ B2, float* __restrict__ C2){
  __shared__ float AsT[32*(MT+1)];
  __shared__ float Bs[32*68];
  if(blockIdx.y == 1){ A = A2; B = B2; C = C2; }
  int bm = blockIdx.x / ntn, bn = blockIdx.x % ntn;
  int m0 = bm*MT, n0 = bn*64;
  int tid = threadIdx.x;
  int tx = tid & 15, ty = tid >> 4;
  float acc[TM][4];
  #pragma unroll
  for(int i = 0; i < TM; i++)
    #pragma unroll
    for(int j = 0; j < 4; j++) acc[i][j] = 0.0f;

  for(int k0 = 0; k0 < K; k0 += 32){
    __syncthreads();
    #pragma unroll
    for(int v = 0; v < MT/32; v++){
      int idx = v*256 + tid;
      int ar = idx >> 3, ac = (idx & 7)*4;
      float4 a4 = *(const float4*)(A + (size_t)(m0+ar)*lda + k0 + ac);
      AsT[(ac+0)*(MT+1) + ar] = a4.x;
      AsT[(ac+1)*(MT+1) + ar] = a4.y;
      AsT[(ac+2)*(MT+1) + ar] = a4.z;
      AsT[(ac+3)*(MT+1) + ar] = a4.w;
    }
    #pragma unroll
    for(int v = 0; v < 2; v++){
      int idx = v*256 + tid;
      int kr = idx >> 4, c4 = (idx & 15)*4;
      *(float4*)(&Bs[kr*68 + c4]) = *(const float4*)(B + (size_t)(k0+kr)*ldb + n0 + c4);
    }
    __syncthreads();
    #pragma unroll
    for(int k = 0; k < 32; k++){
      float av[TM];
      #pragma unroll
      for(int i = 0; i < TM; i++) av[i] = AsT[k*(MT+1) + ty*TM + i];
      float4 bv = *(const float4*)(&Bs[k*68 + tx*4]);
      #pragma unroll
      for(int i = 0; i < TM; i++){
        acc[i][0] = fmaf(av[i], bv.x, acc[i][0]);
        acc[i][1] = fmaf(av[i], bv.y, acc[i][1]);
        acc[i][2] = fmaf(av[i], bv.z, acc[i][2]);
        acc[i][3] = fmaf(av[i], bv.w, acc[i][3]);
      }
    }
  }
  int n = n0 + tx*4;
  float4 bi;
  if(EPI != 0) bi = *(const float4*)(bias + n);
  #pragma unroll
  for(int i = 0; i < TM; i++){
    int m = m0 + ty*TM + i;
    float4 o;
    if(EPI == 0){
      o.x = acc[i][0]; o.y = acc[i][1]; o.z = acc[i][2]; o.w = acc[i][3];
    } else if(EPI == 1){
      o.x = fmaxf(acc[i][0] + bi.x, 0.0f);
      o.y = fmaxf(acc[i][1] + bi.y, 0.0f);
      o.z = fmaxf(acc[i][2] + bi.z, 0.0f);
      o.w = fmaxf(acc[i][3] + bi.w, 0.0f);
    } else {
      float4 rv = *(const float4*)(res + (size_t)m*ldc + n);
      o.x = acc[i][0] + bi.x + rv.x;
      o.y = acc[i][1] + bi.y + rv.y;
      o.z = acc[i][2] + bi.z + rv.z;
      o.w = acc[i][3] + bi.w + rv.w;
    }
    *(float4*)(C + (size_t)m*ldc + n) = o;
  }
}

// ---------------- GRU gate activations + LN(mlp) prep; wave per row ----------------
__global__ __launch_bounds__(256) void k_act(const float* __restrict__ gi,
    const float* __restrict__ gh, const float* __restrict__ den,
    const float* __restrict__ slots, const float* __restrict__ bih,
    const float* __restrict__ bhh, const float* __restrict__ lw,
    const float* __restrict__ lb, float* __restrict__ hp, float* __restrict__ lnh){
  int wv = threadIdx.x >> 6, l = threadIdx.x & 63;
  int row = blockIdx.x*4 + wv;
  const float* gir = gi + (size_t)row*768;
  const float* ghr = gh + (size_t)row*768;
  float invd = 1.0f / den[row];
  float4 air = *(const float4*)(gir + 4*l);
  float4 aiz = *(const float4*)(gir + 256 + 4*l);
  float4 ain = *(const float4*)(gir + 512 + 4*l);
  float4 ahr = *(const float4*)(ghr + 4*l);
  float4 ahz = *(const float4*)(ghr + 256 + 4*l);
  float4 ahn = *(const float4*)(ghr + 512 + 4*l);
  float4 br = *(const float4*)(bih + 4*l);
  float4 bz = *(const float4*)(bih + 256 + 4*l);
  float4 bn = *(const float4*)(bih + 512 + 4*l);
  float4 cr = *(const float4*)(bhh + 4*l);
  float4 cz = *(const float4*)(bhh + 256 + 4*l);
  float4 cn = *(const float4*)(bhh + 512 + 4*l);
  float4 hc = *(const float4*)(slots + (size_t)row*256 + 4*l);
  float4 h;
  #pragma unroll
  for(int i = 0; i < 4; i++){
    float gr = (&air.x)[i]*invd + (&br.x)[i] + (&ahr.x)[i] + (&cr.x)[i];
    float gz = (&aiz.x)[i]*invd + (&bz.x)[i] + (&ahz.x)[i] + (&cz.x)[i];
    float gn = (&ain.x)[i]*invd + (&bn.x)[i];
    float hn = (&ahn.x)[i] + (&cn.x)[i];
    float r = 1.0f/(1.0f + __expf(-gr));
    float z = 1.0f/(1.0f + __expf(-gz));
    float n = tanhf(gn + r*hn);
    (&h.x)[i] = (1.0f - z)*n + z*(&hc.x)[i];
  }
  *(float4*)(hp + (size_t)row*256 + 4*l) = h;
  float s1 = h.x + h.y + h.z + h.w;
  float s2 = h.x*h.x + h.y*h.y + h.z*h.z + h.w*h.w;
  #pragma unroll
  for(int m = 1; m < 64; m <<= 1){ s1 += __shfl_xor(s1, m); s2 += __shfl_xor(s2, m); }
  float mean = s1 * (1.0f/CD);
  float var  = fmaxf(s2 * (1.0f/CD) - mean*mean, 0.0f);
  float rstd = rsqrtf(var + 1e-5f);
  float4 w4 = *(const float4*)(lw + 4*l);
  float4 b4 = *(const float4*)(lb + 4*l);
  float4 o;
  o.x = (h.x - mean)*rstd*w4.x + b4.x;
  o.y = (h.y - mean)*rstd*w4.y + b4.y;
  o.z = (h.z - mean)*rstd*w4.z + b4.z;
  o.w = (h.w - mean)*rstd*w4.w + b4.w;
  *(float4*)(lnh + (size_t)row*256 + 4*l) = o;
}

extern "C" void kernel_launch(void* const* d_in, const int* in_sizes, int n_in,
                              void* d_out, int out_size, void* d_ws, size_t ws_size,
                              hipStream_t stream){
  const float* inputs = (const float*)d_in[0];
  const float* noise  = (const float*)d_in[1];
  const float* ln_in_w = (const float*)d_in[2];
  const float* ln_in_b = (const float*)d_in[3];
  const float* ln_sl_w = (const float*)d_in[4];
  const float* ln_sl_b = (const float*)d_in[5];
  const float* ln_ml_w = (const float*)d_in[6];
  const float* ln_ml_b = (const float*)d_in[7];
  const float* mu   = (const float*)d_in[8];
  const float* lsig = (const float*)d_in[9];
  const float* Wq  = (const float*)d_in[10];
  const float* Wk  = (const float*)d_in[11];
  const float* Wv  = (const float*)d_in[12];
  const float* wih = (const float*)d_in[13];
  const float* whh = (const float*)d_in[14];
  const float* bih = (const float*)d_in[15];
  const float* bhh = (const float*)d_in[16];
  const float* w1  = (const float*)d_in[17];
  const float* b1  = (const float*)d_in[18];
  const float* w2  = (const float*)d_in[19];
  const float* b2  = (const float*)d_in[20];

  char* ws = (char*)d_ws;
  size_t off = 0;
  unsigned short* x = (unsigned short*)(ws + off); off += (size_t)CB*CN*CD*2;
  float* slots = (float*)(ws + off); off += (size_t)CB*CS*CD*4;
  float* hp    = (float*)(ws + off); off += (size_t)CB*CS*CD*4;
  float* U     = (float*)(ws + off); off += (size_t)CB*CS*CD*4;
  float* den   = (float*)(ws + off); off += (size_t)CB*CS*4;
  unsigned short* qt  = (unsigned short*)(ws + off); off += (size_t)CB*16*CD*2;
  unsigned short* M1T = (unsigned short*)(ws + off); off += (size_t)CD*CD*2;
  float* MihT = (float*)(ws + off); off += (size_t)CD*768*4;
  float* WhhT = (float*)(ws + off); off += (size_t)CD*768*4;
  float* w1T  = (float*)(ws + off); off += (size_t)CD*CH*4;
  float* w2T  = (float*)(ws + off); off += (size_t)CH*CD*4;
  float* gi   = (float*)(ws + off); off += (size_t)512*768*4;
  float* gh   = (float*)(ws + off); off += (size_t)512*768*4;
  float* lnh  = (float*)(ws + off); off += (size_t)512*256*4;
  float* h1   = (float*)(ws + off); off += (size_t)512*512*4;

  k_ln<<<4096, 256, 0, stream>>>(inputs, ln_in_w, ln_in_b, x);
  k_setup<<<3328, 256, 0, stream>>>(Wq, Wk, wih, Wv, whh, w1, w2, noise, mu, lsig,
                                    M1T, MihT, WhhT, w1T, w2T, slots);

  for(int it = 0; it < 3; it++){
    k_qt<<<64, 256, 0, stream>>>(slots, ln_sl_w, ln_sl_b, M1T, qt, U, den);
    k_attn<<<1024, 256, 0, stream>>>(x, qt, U, den);
    // gates: gi = U @ MihT [512x768], gh = slots @ WhhT [512x768]
    k_gemm<64, 4, 0><<<dim3(96, 2), 256, 0, stream>>>(
        U, 256, MihT, 768, gi, 768, 256, 12, nullptr, nullptr,
        slots, WhhT, gh);
    k_act<<<128, 256, 0, stream>>>(gi, gh, den, slots, bih, bhh, ln_ml_w, ln_ml_b, hp, lnh);
    // h1 = relu(lnh @ w1T + b1)  [512x512]
    k_gemm<64, 4, 1><<<dim3(64, 1), 256, 0, stream>>>(
        lnh, 256, w1T, 512, h1, 512, 256, 8, b1, nullptr,
        nullptr, nullptr, nullptr);
    // slots_next = h1 @ w2T + b2 + hp  [512x256]; final iter writes d_out directly
    float* cdst = (it == 2) ? (float*)d_out : slots;
    k_gemm<32, 2, 2><<<dim3(64, 1), 256, 0, stream>>>(
        h1, 512, w2T, 256, cdst, 256, 512, 4, b2, hp,
        nullptr, nullptr, nullptr);
  }
}

// Round 4
// 665.901 us; speedup vs baseline: 1.5427x; 1.2089x over previous
//
#include <hip/hip_runtime.h>

#define CB 64
#define CN 4096
#define CD 256
#define CS 8
#define CH 512

typedef __bf16 bf16_t;
typedef bf16_t bf16x8 __attribute__((ext_vector_type(8)));
typedef float f32x4 __attribute__((ext_vector_type(4)));

__device__ __forceinline__ unsigned short f2bf(float f){
  unsigned int u = __builtin_bit_cast(unsigned int, f);
  u += 0x7FFFu + ((u >> 16) & 1u);
  return (unsigned short)(u >> 16);
}

__device__ __forceinline__ f32x4 mfma16(bf16x8 a, bf16x8 b, f32x4 c){
  return __builtin_amdgcn_mfma_f32_16x16x32_bf16(a, b, c, 0, 0, 0);
}

__device__ __forceinline__ void gl_lds16(const void* g, void* l){
  __builtin_amdgcn_global_load_lds(
      (const __attribute__((address_space(1))) unsigned int*)g,
      (__attribute__((address_space(3))) unsigned int*)l, 16, 0, 0);
}

// ---------------- LN over inputs -> x (bf16, row-major) ----------------
__global__ __launch_bounds__(256) void k_ln(const float* __restrict__ in,
    const float* __restrict__ gw, const float* __restrict__ gb,
    unsigned short* __restrict__ x){
  int blk = blockIdx.x;            // 4096 = 64 b * 64 ntiles
  int b = blk >> 6, nt = blk & 63;
  int wv = threadIdx.x >> 6, l = threadIdx.x & 63;
  const float* base = in + ((size_t)b*CN + (size_t)nt*64) * CD;
  unsigned short* xb = x + ((size_t)b*CN + (size_t)nt*64) * CD;
  float4 w4 = *(const float4*)(gw + 4*l);
  float4 b4 = *(const float4*)(gb + 4*l);
  for(int i = 0; i < 16; i++){
    int r = wv*16 + i;
    float4 v = *(const float4*)(base + (size_t)r*CD + 4*l);
    float s1 = v.x + v.y + v.z + v.w;
    float s2 = v.x*v.x + v.y*v.y + v.z*v.z + v.w*v.w;
    #pragma unroll
    for(int m = 1; m < 64; m <<= 1){ s1 += __shfl_xor(s1, m); s2 += __shfl_xor(s2, m); }
    float mean = s1 * (1.0f/CD);
    float var  = fmaxf(s2 * (1.0f/CD) - mean*mean, 0.0f);
    float rstd = rsqrtf(var + 1e-5f);
    float y0 = (v.x - mean)*rstd*w4.x + b4.x;
    float y1 = (v.y - mean)*rstd*w4.y + b4.y;
    float y2 = (v.z - mean)*rstd*w4.z + b4.z;
    float y3 = (v.w - mean)*rstd*w4.w + b4.w;
    uint2 p;
    p.x = (unsigned)f2bf(y0) | ((unsigned)f2bf(y1) << 16);
    p.y = (unsigned)f2bf(y2) | ((unsigned)f2bf(y3) << 16);
    *(uint2*)(xb + (size_t)r*CD + 4*l) = p;
  }
}

// ---------------- fused setup: M1T(bf16), bf16 weights [N][K], slots init ----------------
__global__ __launch_bounds__(256) void k_setup(
    const float* __restrict__ Wq, const float* __restrict__ Wk,
    const float* __restrict__ wih, const float* __restrict__ Wv,
    const float* __restrict__ whh, const float* __restrict__ w1,
    const float* __restrict__ w2, const float* __restrict__ noise,
    const float* __restrict__ mu, const float* __restrict__ lsig,
    unsigned short* __restrict__ M1T, unsigned short* __restrict__ Mih_bf,
    unsigned short* __restrict__ Whh_bf, unsigned short* __restrict__ w1_bf,
    unsigned short* __restrict__ w2_bf, float* __restrict__ slots){
  int bid = blockIdx.x, tid = threadIdx.x;
  if(bid < 256){                       // M1T[ep][e] = scale * sum_d Wq[d][e]*Wk[d][ep]
    int ep = bid, e = tid;
    float acc = 0.0f;
    for(int d = 0; d < 256; d++) acc = fmaf(Wq[(size_t)d*256 + e], Wk[(size_t)d*256 + ep], acc);
    M1T[(size_t)ep*256 + e] = f2bf(acc * 0.0625f);
  } else if(bid < 1024){               // Mih_bf[j][e] = sum_d wih[j][d]*Wv[d][e]  (768x256)
    int j = bid - 256, e = tid;
    float acc = 0.0f;
    for(int d = 0; d < 256; d++) acc = fmaf(wih[(size_t)j*256 + d], Wv[(size_t)d*256 + e], acc);
    Mih_bf[(size_t)j*256 + e] = f2bf(acc);
  } else if(bid < 1792){               // Whh_bf = bf16(whh), 768x256 row-major
    int idx = (bid - 1024)*256 + tid;
    Whh_bf[idx] = f2bf(whh[idx]);
  } else if(bid < 2304){               // w1_bf = bf16(w1), 512x256
    int idx = (bid - 1792)*256 + tid;
    w1_bf[idx] = f2bf(w1[idx]);
  } else if(bid < 2816){               // w2_bf = bf16(w2), 256x512
    int idx = (bid - 2304)*256 + tid;
    w2_bf[idx] = f2bf(w2[idx]);
  } else {                             // slots init, 131072 elems
    int idx = (bid - 2816)*256 + tid;
    int d = idx & 255;
    slots[idx] = mu[d] + __expf(lsig[d]) * noise[idx];
  }
}

// ---------------- qt = scale*LN(slots)@M1 (bf16, rows 8..15 zero); also zeros U,den ----------------
__global__ __launch_bounds__(256) void k_qt(const float* __restrict__ slots,
    const float* __restrict__ lw, const float* __restrict__ lb,
    const unsigned short* __restrict__ M1T, unsigned short* __restrict__ qt,
    float* __restrict__ U, float* __restrict__ den){
  __shared__ unsigned short sn[16*264];
  int b = blockIdx.x;
  int tid = threadIdx.x;
  float4 z4 = {0.f, 0.f, 0.f, 0.f};
  float* Ub = U + (size_t)b*CS*CD;
  *(float4*)(Ub + tid*8)     = z4;
  *(float4*)(Ub + tid*8 + 4) = z4;
  if(tid < CS) den[b*CS + tid] = 0.0f;

  int wv = tid >> 6, l = tid & 63;
  int lm = l & 15, lg = l >> 4;
  float4 w4 = *(const float4*)(lw + 4*l);
  float4 b4 = *(const float4*)(lb + 4*l);
  for(int i = 0; i < 2; i++){
    int r = wv*2 + i;
    float4 v = *(const float4*)(slots + ((size_t)b*CS + r)*CD + 4*l);
    float s1 = v.x + v.y + v.z + v.w;
    float s2 = v.x*v.x + v.y*v.y + v.z*v.z + v.w*v.w;
    #pragma unroll
    for(int m = 1; m < 64; m <<= 1){ s1 += __shfl_xor(s1, m); s2 += __shfl_xor(s2, m); }
    float mean = s1 * (1.0f/CD);
    float var  = fmaxf(s2 * (1.0f/CD) - mean*mean, 0.0f);
    float rstd = rsqrtf(var + 1e-5f);
    float y0 = (v.x - mean)*rstd*w4.x + b4.x;
    float y1 = (v.y - mean)*rstd*w4.y + b4.y;
    float y2 = (v.z - mean)*rstd*w4.z + b4.z;
    float y3 = (v.w - mean)*rstd*w4.w + b4.w;
    uint2 p;
    p.x = (unsigned)f2bf(y0) | ((unsigned)f2bf(y1) << 16);
    p.y = (unsigned)f2bf(y2) | ((unsigned)f2bf(y3) << 16);
    *(uint2*)(&sn[r*264 + 4*l]) = p;
    uint2 zz; zz.x = 0u; zz.y = 0u;
    *(uint2*)(&sn[(r+8)*264 + 4*l]) = zz;
  }
  __syncthreads();
  bf16x8 af[8];
  #pragma unroll
  for(int k = 0; k < 8; k++) af[k] = *(const bf16x8*)(&sn[lm*264 + k*32 + lg*8]);
  #pragma unroll
  for(int ntile = 0; ntile < 4; ntile++){
    int ep = wv*64 + ntile*16 + lm;
    f32x4 acc = {0.f, 0.f, 0.f, 0.f};
    const unsigned short* mrow = M1T + (size_t)ep*CD;
    #pragma unroll
    for(int k = 0; k < 8; k++){
      bf16x8 bf = *(const bf16x8*)(mrow + k*32 + lg*8);
      acc = mfma16(af[k], bf, acc);
    }
    #pragma unroll
    for(int reg = 0; reg < 4; reg++){
      int s = lg*4 + reg;
      qt[((size_t)b*16 + s)*CD + ep] = f2bf(acc[reg]);
    }
  }
}

// ---------------- fused attention pass: logits -> softmax+eps -> U,den ----------------
__global__ __launch_bounds__(256) void k_attn(const unsigned short* __restrict__ x,
    const unsigned short* __restrict__ qt, float* __restrict__ U, float* __restrict__ den){
  __shared__ unsigned short xt[64*256];
  __shared__ unsigned short pt[16*72];
  int b = blockIdx.x >> 4, chunk = blockIdx.x & 15;   // 16 chunks -> 1024 blocks
  int wv = threadIdx.x >> 6, l = threadIdx.x & 63;
  int lm = l & 15, lg = l >> 4;

  bf16x8 qb[8];
  const unsigned short* qrow = qt + ((size_t)b*16 + lm)*CD;
  #pragma unroll
  for(int k = 0; k < 8; k++) qb[k] = *(const bf16x8*)(qrow + k*32 + lg*8);

  f32x4 uacc[4];
  #pragma unroll
  for(int nt = 0; nt < 4; nt++){ f32x4 z = {0.f,0.f,0.f,0.f}; uacc[nt] = z; }
  float dacc = 0.0f;

  const unsigned short* xbatch = x + (size_t)b*CN*CD + (size_t)chunk*256*CD;

  for(int t = 0; t < 4; t++){
    const unsigned short* xtile = xbatch + (size_t)t*64*CD;
    __syncthreads();
    #pragma unroll
    for(int k2 = 0; k2 < 8; k2++){
      int r0 = wv*16 + k2*2;
      int row = r0 + (l >> 5);
      int c = l & 31;
      int f = (row ^ (row >> 3)) & 7;
      const unsigned short* g = xtile + (size_t)row*CD + (size_t)(c ^ f)*8;
      gl_lds16(g, &xt[r0*CD]);
    }
    __syncthreads();

    // phase 1: logits for this wave's 16 rows
    f32x4 c4 = {0.f, 0.f, 0.f, 0.f};
    int rowl = wv*16 + lm;
    int f1 = (rowl ^ (rowl >> 3)) & 7;
    #pragma unroll
    for(int k = 0; k < 8; k++){
      int cc = (k*4 + lg) ^ f1;
      bf16x8 a = *(const bf16x8*)(&xt[rowl*256 + cc*8]);
      c4 = mfma16(a, qb[k], c4);
    }
    // softmax over slots
    float pv[4];
    #pragma unroll
    for(int reg = 0; reg < 4; reg++){
      float v = (lm < 8) ? c4[reg] : -1e30f;
      float mx = v;
      #pragma unroll
      for(int m = 1; m < 16; m <<= 1) mx = fmaxf(mx, __shfl_xor(mx, m));
      float e = __expf(v - mx);
      float s = e;
      #pragma unroll
      for(int m = 1; m < 16; m <<= 1) s += __shfl_xor(s, m);
      float p = (lm < 8) ? (e/s + 1e-8f) : 0.0f;
      dacc += p;
      pv[reg] = p;
    }
    int rbase = wv*16 + lg*4;
    unsigned int p01 = (unsigned)f2bf(pv[0]) | ((unsigned)f2bf(pv[1]) << 16);
    unsigned int p23 = (unsigned)f2bf(pv[2]) | ((unsigned)f2bf(pv[3]) << 16);
    *(unsigned int*)(&pt[lm*72 + rbase])     = p01;
    *(unsigned int*)(&pt[lm*72 + rbase + 2]) = p23;
    __syncthreads();

    // phase 2: U[s, e-slice] += P^T @ X
    #pragma unroll
    for(int ks = 0; ks < 2; ks++){
      bf16x8 a = *(const bf16x8*)(&pt[lm*72 + ks*32 + lg*8]);
      int rb = ks*32 + lg*8;
      #pragma unroll
      for(int nt = 0; nt < 4; nt++){
        int e = wv*64 + nt*16 + lm;
        bf16x8 bfr;
        #pragma unroll
        for(int j = 0; j < 8; j++){
          int row2 = rb + j;
          int f2 = (row2 ^ (row2 >> 3)) & 7;
          int cidx = (e >> 3) ^ f2;
          unsigned short tv = xt[row2*256 + cidx*8 + (e & 7)];
          bfr[j] = __builtin_bit_cast(bf16_t, tv);
        }
        uacc[nt] = mfma16(a, bfr, uacc[nt]);
      }
    }
  }

  // epilogue
  dacc += __shfl_xor(dacc, 16);
  dacc += __shfl_xor(dacc, 32);
  if(l < 8) atomicAdd(&den[b*CS + l], dacc);
  if(lg < 2){
    #pragma unroll
    for(int nt = 0; nt < 4; nt++){
      #pragma unroll
      for(int reg = 0; reg < 4; reg++){
        int s = lg*4 + reg;
        atomicAdd(&U[((size_t)b*CS + s)*CD + wv*64 + nt*16 + lm], uacc[nt][reg]);
      }
    }
  }
}

// ---------------- MFMA bf16 GEMM: C[M x N] = A(fp32)[M x K] @ Bt(bf16)[N x K]^T ----------------
// 64x64 tile per block, 4 waves; A converted fp32->bf16 during LDS staging.
// EPI 0: plain store. EPI 1: relu(acc + bias[n]). EPI 2: acc + bias[n] + res[m][n].
template<int EPI>
__global__ __launch_bounds__(256) void k_gemm_bf(
    const float* __restrict__ A, const unsigned short* __restrict__ Bt,
    float* __restrict__ C, int K, int N, int ntn,
    const float* __restrict__ bias, const float* __restrict__ res,
    const float* __restrict__ A2, const unsigned short* __restrict__ Bt2,
    float* __restrict__ C2){
  __shared__ unsigned short As[64*72];   // stride 72 bf16: b128 reads at 8-dword/bank min
  __shared__ unsigned short Bs[64*72];
  if(blockIdx.y == 1){ A = A2; Bt = Bt2; C = C2; }
  int bm = blockIdx.x / ntn, bn = blockIdx.x % ntn;
  int m0 = bm*64, n0 = bn*64;
  int tid = threadIdx.x;
  int wv = tid >> 6, l = tid & 63, lm = l & 15, lg = l >> 4;
  int sr = tid >> 2, sc = (tid & 3)*8;   // staging: row 0..63, col-chunk of 8

  f32x4 acc[4];
  #pragma unroll
  for(int nt = 0; nt < 4; nt++){ f32x4 z = {0.f,0.f,0.f,0.f}; acc[nt] = z; }

  for(int k0 = 0; k0 < K; k0 += 32){
    __syncthreads();
    {
      const float* src = A + (size_t)(m0 + sr)*K + k0 + sc;
      float4 a0 = *(const float4*)(src);
      float4 a1 = *(const float4*)(src + 4);
      uint4 pk;
      pk.x = (unsigned)f2bf(a0.x) | ((unsigned)f2bf(a0.y) << 16);
      pk.y = (unsigned)f2bf(a0.z) | ((unsigned)f2bf(a0.w) << 16);
      pk.z = (unsigned)f2bf(a1.x) | ((unsigned)f2bf(a1.y) << 16);
      pk.w = (unsigned)f2bf(a1.z) | ((unsigned)f2bf(a1.w) << 16);
      *(uint4*)(&As[sr*72 + sc]) = pk;
      uint4 bv = *(const uint4*)(Bt + (size_t)(n0 + sr)*K + k0 + sc);
      *(uint4*)(&Bs[sr*72 + sc]) = bv;
    }
    __syncthreads();
    bf16x8 af = *(const bf16x8*)(&As[(wv*16 + lm)*72 + lg*8]);
    #pragma unroll
    for(int nt = 0; nt < 4; nt++){
      bf16x8 bf = *(const bf16x8*)(&Bs[(nt*16 + lm)*72 + lg*8]);
      acc[nt] = mfma16(af, bf, acc[nt]);
    }
  }

  #pragma unroll
  for(int nt = 0; nt < 4; nt++){
    int n = n0 + nt*16 + lm;
    float bi = (EPI != 0) ? bias[n] : 0.0f;
    #pragma unroll
    for(int reg = 0; reg < 4; reg++){
      int m = m0 + wv*16 + lg*4 + reg;
      float vv = acc[nt][reg];
      if(EPI == 1) vv = fmaxf(vv + bi, 0.0f);
      else if(EPI == 2) vv = vv + bi + res[(size_t)m*N + n];
      C[(size_t)m*N + n] = vv;
    }
  }
}

// ---------------- GRU gate activations + LN(mlp) prep; wave per row ----------------
__global__ __launch_bounds__(256) void k_act(const float* __restrict__ gi,
    const float* __restrict__ gh, const float* __restrict__ den,
    const float* __restrict__ slots, const float* __restrict__ bih,
    const float* __restrict__ bhh, const float* __restrict__ lw,
    const float* __restrict__ lb, float* __restrict__ hp, float* __restrict__ lnh){
  int wv = threadIdx.x >> 6, l = threadIdx.x & 63;
  int row = blockIdx.x*4 + wv;
  const float* gir = gi + (size_t)row*768;
  const float* ghr = gh + (size_t)row*768;
  float invd = 1.0f / den[row];
  float4 air = *(const float4*)(gir + 4*l);
  float4 aiz = *(const float4*)(gir + 256 + 4*l);
  float4 ain = *(const float4*)(gir + 512 + 4*l);
  float4 ahr = *(const float4*)(ghr + 4*l);
  float4 ahz = *(const float4*)(ghr + 256 + 4*l);
  float4 ahn = *(const float4*)(ghr + 512 + 4*l);
  float4 br = *(const float4*)(bih + 4*l);
  float4 bz = *(const float4*)(bih + 256 + 4*l);
  float4 bn = *(const float4*)(bih + 512 + 4*l);
  float4 cr = *(const float4*)(bhh + 4*l);
  float4 cz = *(const float4*)(bhh + 256 + 4*l);
  float4 cn = *(const float4*)(bhh + 512 + 4*l);
  float4 hc = *(const float4*)(slots + (size_t)row*256 + 4*l);
  float4 h;
  #pragma unroll
  for(int i = 0; i < 4; i++){
    float gr = (&air.x)[i]*invd + (&br.x)[i] + (&ahr.x)[i] + (&cr.x)[i];
    float gz = (&aiz.x)[i]*invd + (&bz.x)[i] + (&ahz.x)[i] + (&cz.x)[i];
    float gn = (&ain.x)[i]*invd + (&bn.x)[i];
    float hn = (&ahn.x)[i] + (&cn.x)[i];
    float r = 1.0f/(1.0f + __expf(-gr));
    float z = 1.0f/(1.0f + __expf(-gz));
    float n = tanhf(gn + r*hn);
    (&h.x)[i] = (1.0f - z)*n + z*(&hc.x)[i];
  }
  *(float4*)(hp + (size_t)row*256 + 4*l) = h;
  float s1 = h.x + h.y + h.z + h.w;
  float s2 = h.x*h.x + h.y*h.y + h.z*h.z + h.w*h.w;
  #pragma unroll
  for(int m = 1; m < 64; m <<= 1){ s1 += __shfl_xor(s1, m); s2 += __shfl_xor(s2, m); }
  float mean = s1 * (1.0f/CD);
  float var  = fmaxf(s2 * (1.0f/CD) - mean*mean, 0.0f);
  float rstd = rsqrtf(var + 1e-5f);
  float4 w4 = *(const float4*)(lw + 4*l);
  float4 b4 = *(const float4*)(lb + 4*l);
  float4 o;
  o.x = (h.x - mean)*rstd*w4.x + b4.x;
  o.y = (h.y - mean)*rstd*w4.y + b4.y;
  o.z = (h.z - mean)*rstd*w4.z + b4.z;
  o.w = (h.w - mean)*rstd*w4.w + b4.w;
  *(float4*)(lnh + (size_t)row*256 + 4*l) = o;
}

extern "C" void kernel_launch(void* const* d_in, const int* in_sizes, int n_in,
                              void* d_out, int out_size, void* d_ws, size_t ws_size,
                              hipStream_t stream){
  const float* inputs = (const float*)d_in[0];
  const float* noise  = (const float*)d_in[1];
  const float* ln_in_w = (const float*)d_in[2];
  const float* ln_in_b = (const float*)d_in[3];
  const float* ln_sl_w = (const float*)d_in[4];
  const float* ln_sl_b = (const float*)d_in[5];
  const float* ln_ml_w = (const float*)d_in[6];
  const float* ln_ml_b = (const float*)d_in[7];
  const float* mu   = (const float*)d_in[8];
  const float* lsig = (const float*)d_in[9];
  const float* Wq  = (const float*)d_in[10];
  const float* Wk  = (const float*)d_in[11];
  const float* Wv  = (const float*)d_in[12];
  const float* wih = (const float*)d_in[13];
  const float* whh = (const float*)d_in[14];
  const float* bih = (const float*)d_in[15];
  const float* bhh = (const float*)d_in[16];
  const float* w1  = (const float*)d_in[17];
  const float* b1  = (const float*)d_in[18];
  const float* w2  = (const float*)d_in[19];
  const float* b2  = (const float*)d_in[20];

  char* ws = (char*)d_ws;
  size_t off = 0;
  unsigned short* x = (unsigned short*)(ws + off); off += (size_t)CB*CN*CD*2;
  float* slots = (float*)(ws + off); off += (size_t)CB*CS*CD*4;
  float* hp    = (float*)(ws + off); off += (size_t)CB*CS*CD*4;
  float* U     = (float*)(ws + off); off += (size_t)CB*CS*CD*4;
  float* den   = (float*)(ws + off); off += (size_t)CB*CS*4;
  unsigned short* qt     = (unsigned short*)(ws + off); off += (size_t)CB*16*CD*2;
  unsigned short* M1T    = (unsigned short*)(ws + off); off += (size_t)CD*CD*2;
  unsigned short* Mih_bf = (unsigned short*)(ws + off); off += (size_t)768*CD*2;
  unsigned short* Whh_bf = (unsigned short*)(ws + off); off += (size_t)768*CD*2;
  unsigned short* w1_bf  = (unsigned short*)(ws + off); off += (size_t)CH*CD*2;
  unsigned short* w2_bf  = (unsigned short*)(ws + off); off += (size_t)CD*CH*2;
  float* gi   = (float*)(ws + off); off += (size_t)512*768*4;
  float* gh   = (float*)(ws + off); off += (size_t)512*768*4;
  float* lnh  = (float*)(ws + off); off += (size_t)512*256*4;
  float* h1   = (float*)(ws + off); off += (size_t)512*512*4;

  k_ln<<<4096, 256, 0, stream>>>(inputs, ln_in_w, ln_in_b, x);
  k_setup<<<3328, 256, 0, stream>>>(Wq, Wk, wih, Wv, whh, w1, w2, noise, mu, lsig,
                                    M1T, Mih_bf, Whh_bf, w1_bf, w2_bf, slots);

  for(int it = 0; it < 3; it++){
    k_qt<<<64, 256, 0, stream>>>(slots, ln_sl_w, ln_sl_b, M1T, qt, U, den);
    k_attn<<<1024, 256, 0, stream>>>(x, qt, U, den);
    // gates: gi = U @ Mih^T [512x768], gh = slots @ Whh^T [512x768]   (K=256, N=768)
    k_gemm_bf<0><<<dim3(96, 2), 256, 0, stream>>>(
        U, Mih_bf, gi, 256, 768, 12, nullptr, nullptr,
        slots, Whh_bf, gh);
    k_act<<<128, 256, 0, stream>>>(gi, gh, den, slots, bih, bhh, ln_ml_w, ln_ml_b, hp, lnh);
    // h1 = relu(lnh @ w1^T + b1)  [512x512]  (K=256, N=512)
    k_gemm_bf<1><<<dim3(64, 1), 256, 0, stream>>>(
        lnh, w1_bf, h1, 256, 512, 8, b1, nullptr,
        nullptr, nullptr, nullptr);
    // slots_next = h1 @ w2^T + b2 + hp  [512x256]  (K=512, N=256); last iter -> d_out
    float* cdst = (it == 2) ? (float*)d_out : slots;
    k_gemm_bf<2><<<dim3(32, 1), 256, 0, stream>>>(
        h1, w2_bf, cdst, 512, 256, 4, b2, hp,
        nullptr, nullptr, nullptr);
  }
}